// Round 12
// baseline (60.833 us; speedup 1.0000x reference)
//
#include <hip/hip_runtime.h>

#define B_SZ 256
#define N_SZ 2000
#define N_PAD 2048
#define D_SZ 512
#define C_SZ 100
#define BT 4             // batch rows per block
#define JW 4             // H8 groups (8 d's each) per block = 32 d's
#define ZSPLIT 16        // D_SZ / 32
#define D4 (D_SZ / 4)
#define DC8 (D_SZ / 8)   // 64 H8 rows in supH

typedef __fp16 h2 __attribute__((ext_vector_type(2)));

struct alignas(16) H8 { h2 x, y, z, w; };  // 8 consecutive halves
struct alignas(8)  H4 { h2 lo, hi; };      // 4 consecutive halves

static __device__ __forceinline__ h2 habs2(h2 v) {
    unsigned u = __builtin_bit_cast(unsigned, v) & 0x7FFF7FFFu;
    return __builtin_bit_cast(h2, u);
}

#if __has_builtin(__builtin_amdgcn_fdot2)
static __device__ __forceinline__ float DOT2(h2 d, h2 wv, float c) {
    return __builtin_amdgcn_fdot2(d, wv, c, false);
}
#else
static __device__ __forceinline__ float DOT2(h2 d, h2 wv, float c) {
    return c + (float)d.x * (float)wv.x + (float)d.y * (float)wv.y;
}
#endif

// ---------------------------------------------------------------------------
// Setup (fused): labels->idx | w->f16 | inputs->f16
// ---------------------------------------------------------------------------
__global__ void setup_kernel(const float* __restrict__ labels,
                             const float* __restrict__ inputs,
                             const float* __restrict__ w,
                             int* __restrict__ idx,
                             H4* __restrict__ inpH4,
                             __fp16* __restrict__ wH) {
    int bid = blockIdx.x, tid = threadIdx.x;
    if (bid < 8) {                       // label scan -> class index
        int n = bid * 256 + tid;
        if (n < N_SZ) {
            const float4* row = (const float4*)(labels + (size_t)n * C_SZ);
            int c = 0;
#pragma unroll
            for (int j = 0; j < C_SZ / 4; ++j) {
                float4 v = row[j];
                if (v.x > 0.5f) c = 4 * j + 0;
                if (v.y > 0.5f) c = 4 * j + 1;
                if (v.z > 0.5f) c = 4 * j + 2;
                if (v.w > 0.5f) c = 4 * j + 3;
            }
            idx[n] = c;
        }
    } else if (bid == 8) {               // w convert
        wH[tid]       = (__fp16)w[tid];
        wH[tid + 256] = (__fp16)w[tid + 256];
    } else {                             // inputs convert (float4 -> H4)
        int i4 = (bid - 9) * 256 + tid;  // 32768 float4s -> 128 blocks
        float4 v = ((const float4*)inputs)[i4];
        H4 o;
        o.lo = __builtin_amdgcn_cvt_pkrtz(v.x, v.y);
        o.hi = __builtin_amdgcn_cvt_pkrtz(v.z, v.w);
        inpH4[i4] = o;
    }
}

// ---------------------------------------------------------------------------
// Transpose+convert support: [N][D] f32 -> supH[DC8][N_PAD] H8 (8 d's/elem)
// ---------------------------------------------------------------------------
__global__ void transposeH_kernel(const float4* __restrict__ sup4,
                                  H8* __restrict__ supH) {
    int t = blockIdx.x * 256 + threadIdx.x; // t = dc8 * N_PAD + n
    int dc8 = t >> 11;
    int n   = t & (N_PAD - 1);
    H8 o = {};
    if (n < N_SZ) {
        float4 p = sup4[(size_t)n * D4 + 2 * dc8];
        float4 q = sup4[(size_t)n * D4 + 2 * dc8 + 1];
        o.x = __builtin_amdgcn_cvt_pkrtz(p.x, p.y);
        o.y = __builtin_amdgcn_cvt_pkrtz(p.z, p.w);
        o.z = __builtin_amdgcn_cvt_pkrtz(q.x, q.y);
        o.w = __builtin_amdgcn_cvt_pkrtz(q.z, q.w);
    }
    supH[t] = o;
}

// ---------------------------------------------------------------------------
// Main (n-sweep, f16 packed) — byte-identical to round 10.
// Launched TWICE this round (idempotent S writes) so that
// dur_us(total) - dur_us(round10) = true score duration.
// ---------------------------------------------------------------------------
__global__ __launch_bounds__(256, 3) void score_kernel(
    const H8* __restrict__ inpH8,   // [B][DC8]
    const H8* __restrict__ supH,    // [DC8][N_PAD]
    const H8* __restrict__ wH8,     // [DC8]
    float* __restrict__ S)          // [ZSPLIT][B][N_PAD]
{
    int tid = threadIdx.x;
    int b0  = blockIdx.x * BT;
    int dc0 = blockIdx.y * JW;      // H8-row base (32 d's)

    unsigned vz = 0;                // opaque zero: force vector regs
    asm volatile("" : "+v"(vz));

    H8 af[BT][JW];
    H8 wf[JW];
#pragma unroll
    for (int i = 0; i < BT; ++i) {
        const H8* ap = inpH8 + (size_t)(b0 + i) * DC8 + dc0 + vz;
#pragma unroll
        for (int j = 0; j < JW; ++j) af[i][j] = ap[j];
    }
    {
        const H8* wp = wH8 + dc0 + vz;
#pragma unroll
        for (int j = 0; j < JW; ++j) wf[j] = wp[j];
    }

    const H8* sp0 = supH + (size_t)(dc0 + 0) * N_PAD + tid;
    const H8* sp1 = supH + (size_t)(dc0 + 1) * N_PAD + tid;
    const H8* sp2 = supH + (size_t)(dc0 + 2) * N_PAD + tid;
    const H8* sp3 = supH + (size_t)(dc0 + 3) * N_PAD + tid;

    float* Sp0 = S + ((size_t)blockIdx.y * B_SZ + b0) * N_PAD + tid;

#define STEP(J, SV)                                                  \
    {                                                                \
        H8 wv = wf[J];                                               \
        _Pragma("unroll") for (int i = 0; i < BT; ++i) {             \
            H8 a = af[i][J];                                         \
            acc[i] = DOT2(habs2(a.x - SV.x), wv.x, acc[i]);          \
            acc[i] = DOT2(habs2(a.y - SV.y), wv.y, acc[i]);          \
            acc[i] = DOT2(habs2(a.z - SV.z), wv.z, acc[i]);          \
            acc[i] = DOT2(habs2(a.w - SV.w), wv.w, acc[i]);          \
        }                                                            \
    }

    H8 sv0 = sp0[0], sv1 = sp1[0], sv2 = sp2[0], sv3 = sp3[0];

#pragma unroll 1
    for (int n0 = 0; n0 < N_PAD - 256; n0 += 256) {
        float acc[BT] = {0.f, 0.f, 0.f, 0.f};
        H8 nx0 = sp0[n0 + 256];
        STEP(0, sv0);
        H8 nx1 = sp1[n0 + 256];
        STEP(1, sv1);
        H8 nx2 = sp2[n0 + 256];
        STEP(2, sv2);
        H8 nx3 = sp3[n0 + 256];
        STEP(3, sv3);
#pragma unroll
        for (int i = 0; i < BT; ++i)
            Sp0[(size_t)i * N_PAD + n0] = acc[i];
        sv0 = nx0; sv1 = nx1; sv2 = nx2; sv3 = nx3;
    }
    {   // epilogue n-step
        float acc[BT] = {0.f, 0.f, 0.f, 0.f};
        STEP(0, sv0); STEP(1, sv1); STEP(2, sv2); STEP(3, sv3);
#pragma unroll
        for (int i = 0; i < BT; ++i)
            Sp0[(size_t)i * N_PAD + (N_PAD - 256)] = acc[i];
    }
#undef STEP
}

// ---------------------------------------------------------------------------
// Aggregate: one 512-thread block per batch row. Sum 16 partials + bias ->
// sigmoid -> LDS class bins -> divide_no_nan.
// ---------------------------------------------------------------------------
__global__ void agg_kernel(const float* __restrict__ S,
                           const int* __restrict__ idx,
                           const float* __restrict__ bias_p,
                           float* __restrict__ out) {
    __shared__ float sums[C_SZ];
    __shared__ float cnts[C_SZ];
    int b = blockIdx.x;
    int t = threadIdx.x;
    if (t < C_SZ) { sums[t] = 0.f; cnts[t] = 0.f; }
    __syncthreads();
    float bias = *bias_p;
    for (int n = t; n < N_SZ; n += 512) {
        float logit = bias;
#pragma unroll
        for (int z = 0; z < ZSPLIT; ++z)
            logit += S[((size_t)z * B_SZ + b) * N_PAD + n];
        float s = 1.0f / (1.0f + __expf(-logit));
        int c = idx[n];
        atomicAdd(&sums[c], s);
        atomicAdd(&cnts[c], 1.0f);
    }
    __syncthreads();
    if (t < C_SZ) {
        float cnt = cnts[t];
        out[(size_t)b * C_SZ + t] = (cnt != 0.f) ? sums[t] / cnt : 0.f;
    }
}

extern "C" void kernel_launch(void* const* d_in, const int* in_sizes, int n_in,
                              void* d_out, int out_size, void* d_ws, size_t ws_size,
                              hipStream_t stream) {
    const float* inputs  = (const float*)d_in[0]; // [B, D]
    const float* support = (const float*)d_in[1]; // [N, D]
    const float* labels  = (const float*)d_in[2]; // [N, C]
    const float* w       = (const float*)d_in[3]; // [D]
    const float* bias    = (const float*)d_in[4]; // [1]
    float* out = (float*)d_out;                   // [B, C]

    // ws layout (bytes): idx@0 (8K) | wH@8K (1K) | inpH@16K (256K) |
    // supH@512K (2M) | S@4M (32M). All regions fully written before read.
    int*     idx  = (int*)d_ws;
    __fp16*  wH   = (__fp16*)((char*)d_ws + 8192);
    __fp16*  inpH = (__fp16*)((char*)d_ws + 16384);
    H8*      supH = (H8*)((char*)d_ws + 524288);
    float*   S    = (float*)((char*)d_ws + 4 * 1024 * 1024);

    setup_kernel<<<dim3(9 + B_SZ * D_SZ / 4 / 256), dim3(256), 0, stream>>>(
        labels, inputs, w, idx, (H4*)inpH, wH);

    transposeH_kernel<<<dim3(DC8 * N_PAD / 256), dim3(256), 0, stream>>>(
        (const float4*)support, supH);

    dim3 grid(B_SZ / BT, ZSPLIT); // 64 x 16 = 1024 blocks
    // Launched twice: second launch rewrites identical values into S
    // (idempotent, deterministic). Delta vs round-10 total isolates the
    // true score_kernel duration, immune to top-5 profile truncation.
    score_kernel<<<grid, dim3(256), 0, stream>>>(
        (const H8*)inpH, supH, (const H8*)wH, S);
    score_kernel<<<grid, dim3(256), 0, stream>>>(
        (const H8*)inpH, supH, (const H8*)wH, S);

    agg_kernel<<<dim3(B_SZ), dim3(512), 0, stream>>>(S, idx, bias, out);
}

// Round 13
// 45.616 us; speedup vs baseline: 1.3336x; 1.3336x over previous
//
#include <hip/hip_runtime.h>

#define B_SZ 256
#define N_SZ 2000
#define N_PAD 2048
#define D_SZ 512
#define C_SZ 100
#define BT 4            // batch rows per block
#define NT 128          // n's per block (= block size)
#define D4 (D_SZ / 4)
#define DC8 (D_SZ / 8)  // 64 H8 rows in supH
#define DHALF (DC8 / 2) // 32 H8 rows per d-half

typedef __fp16 h2 __attribute__((ext_vector_type(2)));

struct alignas(16) H8 { h2 x, y, z, w; };  // 8 consecutive halves
struct alignas(8)  H4 { h2 lo, hi; };      // 4 consecutive halves

static __device__ __forceinline__ h2 habs2(h2 v) {
    unsigned u = __builtin_bit_cast(unsigned, v) & 0x7FFF7FFFu;
    return __builtin_bit_cast(h2, u);
}

#if __has_builtin(__builtin_amdgcn_fdot2)
static __device__ __forceinline__ float DOT2(h2 d, h2 wv, float c) {
    return __builtin_amdgcn_fdot2(d, wv, c, false);
}
#else
static __device__ __forceinline__ float DOT2(h2 d, h2 wv, float c) {
    return c + (float)d.x * (float)wv.x + (float)d.y * (float)wv.y;
}
#endif

// ---------------------------------------------------------------------------
// Setup (fused): labels->idx | w->f16 | inputs->f16
// ---------------------------------------------------------------------------
__global__ void setup_kernel(const float* __restrict__ labels,
                             const float* __restrict__ inputs,
                             const float* __restrict__ w,
                             int* __restrict__ idx,
                             H4* __restrict__ inpH4,
                             __fp16* __restrict__ wH) {
    int bid = blockIdx.x, tid = threadIdx.x;
    if (bid < 8) {                       // label scan -> class index
        int n = bid * 256 + tid;
        if (n < N_SZ) {
            const float4* row = (const float4*)(labels + (size_t)n * C_SZ);
            int c = 0;
#pragma unroll
            for (int j = 0; j < C_SZ / 4; ++j) {
                float4 v = row[j];
                if (v.x > 0.5f) c = 4 * j + 0;
                if (v.y > 0.5f) c = 4 * j + 1;
                if (v.z > 0.5f) c = 4 * j + 2;
                if (v.w > 0.5f) c = 4 * j + 3;
            }
            idx[n] = c;
        }
    } else if (bid == 8) {               // w convert
        wH[tid]       = (__fp16)w[tid];
        wH[tid + 256] = (__fp16)w[tid + 256];
    } else {                             // inputs convert (float4 -> H4)
        int i4 = (bid - 9) * 256 + tid;  // 32768 float4s -> 128 blocks
        float4 v = ((const float4*)inputs)[i4];
        H4 o;
        o.lo = __builtin_amdgcn_cvt_pkrtz(v.x, v.y);
        o.hi = __builtin_amdgcn_cvt_pkrtz(v.z, v.w);
        inpH4[i4] = o;
    }
}

// ---------------------------------------------------------------------------
// Transpose+convert support: [N][D] f32 -> supH[DC8][N_PAD] H8 (8 d's/elem)
// ---------------------------------------------------------------------------
__global__ void transposeH_kernel(const float4* __restrict__ sup4,
                                  H8* __restrict__ supH) {
    int t = blockIdx.x * 256 + threadIdx.x; // t = dc8 * N_PAD + n
    int dc8 = t >> 11;
    int n   = t & (N_PAD - 1);
    H8 o = {};
    if (n < N_SZ) {
        float4 p = sup4[(size_t)n * D4 + 2 * dc8];
        float4 q = sup4[(size_t)n * D4 + 2 * dc8 + 1];
        o.x = __builtin_amdgcn_cvt_pkrtz(p.x, p.y);
        o.y = __builtin_amdgcn_cvt_pkrtz(p.z, p.w);
        o.z = __builtin_amdgcn_cvt_pkrtz(q.x, q.y);
        o.w = __builtin_amdgcn_cvt_pkrtz(q.z, q.w);
    }
    supH[t] = o;
}

// ---------------------------------------------------------------------------
// Main. Round-12 probe: r10 score = 18.8us, the other ~23us was ZSPLIT=16's
// 32MB partial traffic + overhead. Fix: block = (BT=4 b-rows x NT=128 n's x
// half of D), d looped IN-BLOCK with register acc -> partials shrink to
// S2[2][B][N_PAD] = 4MB (L2-resident). af/wf reloaded per 2-row step as
// one-time uniform 16B vector loads (L2-hot, vz trick keeps them vector);
// support stream coalesced per-lane, one pair ahead. Grid 2048 blocks ->
// 8 blocks/CU, 4 waves/SIMD.
// ---------------------------------------------------------------------------
__global__ __launch_bounds__(NT, 4) void score_kernel(
    const H8* __restrict__ inpH8,   // [B][DC8]
    const H8* __restrict__ supH,    // [DC8][N_PAD]
    const H8* __restrict__ wH8,     // [DC8]
    float* __restrict__ S2)         // [2][B][N_PAD] half-logits
{
    int tid = threadIdx.x;
    int n   = blockIdx.y * NT + tid;
    int b0  = blockIdx.x * BT;
    int dz  = blockIdx.z;
    int dcb = dz * DHALF;           // 0 or 32

    unsigned vz = 0;                // opaque zero: force vector path
    asm volatile("" : "+v"(vz));

    const H8* __restrict__ a0 = inpH8 + (size_t)(b0 + 0) * DC8 + dcb + vz;
    const H8* __restrict__ a1 = inpH8 + (size_t)(b0 + 1) * DC8 + dcb + vz;
    const H8* __restrict__ a2 = inpH8 + (size_t)(b0 + 2) * DC8 + dcb + vz;
    const H8* __restrict__ a3 = inpH8 + (size_t)(b0 + 3) * DC8 + dcb + vz;
    const H8* __restrict__ wp = wH8 + dcb + vz;
    const H8* __restrict__ sp = supH + (size_t)dcb * N_PAD + n;

    float acc[BT] = {0.f, 0.f, 0.f, 0.f};

#define ROW(AP, I, DC, SV, WV)                                       \
    {                                                                \
        H8 a = AP[DC];                                               \
        acc[I] = DOT2(habs2(a.x - SV.x), WV.x, acc[I]);              \
        acc[I] = DOT2(habs2(a.y - SV.y), WV.y, acc[I]);              \
        acc[I] = DOT2(habs2(a.z - SV.z), WV.z, acc[I]);              \
        acc[I] = DOT2(habs2(a.w - SV.w), WV.w, acc[I]);              \
    }

#define PAIR(DC, S0, S1)                                             \
    {                                                                \
        H8 w0 = wp[DC], w1 = wp[(DC) + 1];                           \
        ROW(a0, 0, (DC), S0, w0)                                     \
        ROW(a1, 1, (DC), S0, w0)                                     \
        ROW(a2, 2, (DC), S0, w0)                                     \
        ROW(a3, 3, (DC), S0, w0)                                     \
        ROW(a0, 0, (DC) + 1, S1, w1)                                 \
        ROW(a1, 1, (DC) + 1, S1, w1)                                 \
        ROW(a2, 2, (DC) + 1, S1, w1)                                 \
        ROW(a3, 3, (DC) + 1, S1, w1)                                 \
    }

    // software pipeline over d-rows: support pair prefetched one step ahead
    H8 s0 = sp[0];
    H8 s1 = sp[(size_t)1 * N_PAD];

#pragma unroll 1
    for (int dc = 0; dc < DHALF - 2; dc += 2) {
        H8 p0 = sp[(size_t)(dc + 2) * N_PAD];
        H8 p1 = sp[(size_t)(dc + 3) * N_PAD];
        PAIR(dc, s0, s1);
        s0 = p0; s1 = p1;
    }
    PAIR(DHALF - 2, s0, s1);
#undef PAIR
#undef ROW

    float* __restrict__ Sp = S2 + ((size_t)dz * B_SZ + b0) * N_PAD + n;
#pragma unroll
    for (int i = 0; i < BT; ++i)
        Sp[(size_t)i * N_PAD] = acc[i];   // coalesced; 4 MB total
}

// ---------------------------------------------------------------------------
// Aggregate: one block per batch row. logit = S2[0]+S2[1]+bias -> sigmoid ->
// LDS class bins -> divide_no_nan. 4 MB read total, L2-resident.
// ---------------------------------------------------------------------------
__global__ void agg_kernel(const float* __restrict__ S2,
                           const int* __restrict__ idx,
                           const float* __restrict__ bias_p,
                           float* __restrict__ out) {
    __shared__ float sums[C_SZ];
    __shared__ float cnts[C_SZ];
    int b = blockIdx.x;
    int t = threadIdx.x;
    if (t < C_SZ) { sums[t] = 0.f; cnts[t] = 0.f; }
    __syncthreads();
    float bias = *bias_p;
    for (int n = t; n < N_SZ; n += 256) {
        float logit = bias + S2[(size_t)b * N_PAD + n]
                           + S2[((size_t)B_SZ + b) * N_PAD + n];
        float s = 1.0f / (1.0f + __expf(-logit));
        int c = idx[n];
        atomicAdd(&sums[c], s);
        atomicAdd(&cnts[c], 1.0f);
    }
    __syncthreads();
    if (t < C_SZ) {
        float cnt = cnts[t];
        out[(size_t)b * C_SZ + t] = (cnt != 0.f) ? sums[t] / cnt : 0.f;
    }
}

extern "C" void kernel_launch(void* const* d_in, const int* in_sizes, int n_in,
                              void* d_out, int out_size, void* d_ws, size_t ws_size,
                              hipStream_t stream) {
    const float* inputs  = (const float*)d_in[0]; // [B, D]
    const float* support = (const float*)d_in[1]; // [N, D]
    const float* labels  = (const float*)d_in[2]; // [N, C]
    const float* w       = (const float*)d_in[3]; // [D]
    const float* bias    = (const float*)d_in[4]; // [1]
    float* out = (float*)d_out;                   // [B, C]

    // ws layout (bytes): idx@0 (8K) | wH@8K (1K) | inpH@16K (256K) |
    // supH@512K (2M) | S2@4M (4MB = [2][B][N_PAD] f32). All written
    // before read; no zeroing needed.
    int*     idx  = (int*)d_ws;
    __fp16*  wH   = (__fp16*)((char*)d_ws + 8192);
    __fp16*  inpH = (__fp16*)((char*)d_ws + 16384);
    H8*      supH = (H8*)((char*)d_ws + 524288);
    float*   S2   = (float*)((char*)d_ws + 4 * 1024 * 1024);

    setup_kernel<<<dim3(9 + B_SZ * D_SZ / 4 / 256), dim3(256), 0, stream>>>(
        labels, inputs, w, idx, (H4*)inpH, wH);

    transposeH_kernel<<<dim3(DC8 * N_PAD / 256), dim3(256), 0, stream>>>(
        (const float4*)support, supH);

    dim3 grid(B_SZ / BT, N_PAD / NT, 2); // 64 x 16 x 2 = 2048 blocks
    score_kernel<<<grid, dim3(NT), 0, stream>>>(
        (const H8*)inpH, supH, (const H8*)wH, S2);

    agg_kernel<<<dim3(B_SZ), dim3(256), 0, stream>>>(S2, idx, bias, out);
}